// Round 2
// baseline (3884.938 us; speedup 1.0000x reference)
//
#include <hip/hip_runtime.h>

// B=4, H=16, L=1024, D=1024, DH=64, P=1024
// q,k,v stored in ws as [B,H,L,DH] fp32

#define SCALE 0.125f  // 1/sqrt(64)

__device__ __forceinline__ int swz(int row, int u) {
    // 64-float rows = 16 float4 units; XOR-swizzle kills stride-64 conflicts
    return (row << 4) | (u ^ ((row >> 2) & 15));
}

__device__ __forceinline__ unsigned pack_bf16(float a, float b) {
    unsigned ua = __builtin_bit_cast(unsigned, a);
    unsigned ub = __builtin_bit_cast(unsigned, b);
    ua = (ua + 0x7FFFu + ((ua >> 16) & 1u)) >> 16;   // RNE
    ub = (ub + 0x7FFFu + ((ub >> 16) & 1u)) >> 16;
    return ua | (ub << 16);
}

// ---------------- projection GEMM (unchanged) ----------------
__global__ __launch_bounds__(256) void proj_kernel(
    const float* __restrict__ X, const float* __restrict__ W,
    const float* __restrict__ bias, float* __restrict__ out)
{
    __shared__ float4 As4[16 * 32];  // [k][m] transposed, 16x128 floats
    __shared__ float4 Bs4[16 * 32];  // [k][n], 16x128 floats
    const int tid = threadIdx.x;
    const int bm = blockIdx.y * 128;
    const int bn = blockIdx.x * 128;
    const int ty = tid >> 4, tx = tid & 15;
    const float4* X4 = (const float4*)X;
    const float4* W4 = (const float4*)W;
    float* AsF = (float*)As4;

    float acc[2][2][4][4];
#pragma unroll
    for (int a = 0; a < 2; ++a)
#pragma unroll
        for (int b = 0; b < 2; ++b)
#pragma unroll
            for (int i = 0; i < 4; ++i)
#pragma unroll
                for (int j = 0; j < 4; ++j) acc[a][b][i][j] = 0.f;

    for (int k0 = 0; k0 < 1024; k0 += 16) {
        __syncthreads();
#pragma unroll
        for (int it = 0; it < 2; ++it) {
            int idx = tid + it * 256;
            int m = idx >> 2, kc = idx & 3;
            float4 x = X4[(size_t)(bm + m) * 256 + (k0 >> 2) + kc];
            AsF[(kc * 4 + 0) * 128 + m] = x.x;
            AsF[(kc * 4 + 1) * 128 + m] = x.y;
            AsF[(kc * 4 + 2) * 128 + m] = x.z;
            AsF[(kc * 4 + 3) * 128 + m] = x.w;
        }
#pragma unroll
        for (int it = 0; it < 2; ++it) {
            int idx = tid + it * 256;
            int k = idx >> 5, un = idx & 31;
            Bs4[k * 32 + un] = W4[(size_t)(k0 + k) * 256 + (bn >> 2) + un];
        }
        __syncthreads();
#pragma unroll
        for (int kk = 0; kk < 16; ++kk) {
            float4 a0 = As4[kk * 32 + ty];
            float4 a1 = As4[kk * 32 + 16 + ty];
            float4 b0 = Bs4[kk * 32 + tx];
            float4 b1 = Bs4[kk * 32 + 16 + tx];
            float av[2][4] = {{a0.x, a0.y, a0.z, a0.w}, {a1.x, a1.y, a1.z, a1.w}};
            float bw[2][4] = {{b0.x, b0.y, b0.z, b0.w}, {b1.x, b1.y, b1.z, b1.w}};
#pragma unroll
            for (int rh = 0; rh < 2; ++rh)
#pragma unroll
                for (int ch = 0; ch < 2; ++ch)
#pragma unroll
                    for (int i = 0; i < 4; ++i)
#pragma unroll
                        for (int j = 0; j < 4; ++j)
                            acc[rh][ch][i][j] += av[rh][i] * bw[ch][j];
        }
    }
    const float4* bias4 = (const float4*)bias;
#pragma unroll
    for (int rh = 0; rh < 2; ++rh)
#pragma unroll
        for (int ch = 0; ch < 2; ++ch) {
            float4 bv4 = bias4[(bn >> 2) + ch * 16 + tx];
#pragma unroll
            for (int i = 0; i < 4; ++i) {
                int m = bm + rh * 64 + ty * 4 + i;
                int n = bn + ch * 64 + tx * 4;
                int b = m >> 10, l = m & 1023;
                int h = n >> 6, d = n & 63;
                float4 o;
                o.x = acc[rh][ch][i][0] + bv4.x;
                o.y = acc[rh][ch][i][1] + bv4.y;
                o.z = acc[rh][ch][i][2] + bv4.z;
                o.w = acc[rh][ch][i][3] + bv4.w;
                *(float4*)&out[(((size_t)b * 16 + h) * 1024 + l) * 64 + d] = o;
            }
        }
}

// ---------------- fused attention with relative_key_query bias ----------------
// one block = (b, h, 64 q-rows); Q in regs; K/P union; De in bf16; softmax via shfl
__global__ __launch_bounds__(256, 2) void attn_kernel(
    const float* __restrict__ Q, const float* __restrict__ K,
    const float* __restrict__ V, const float* __restrict__ mask,
    const float* __restrict__ de, float* __restrict__ out)
{
    __shared__ float4 KPs[64 * 16];   // K tile during S-phase; P tile during PV
    __shared__ float4 Vs[64 * 16];
    __shared__ uint2  Des[127 * 16];  // bf16x4 per 8B unit, swizzled

    const int tid = threadIdx.x;
    const int ty = tid >> 4, tx = tid & 15;   // 16x16 thread grid, 4x4 micro-tile
    const int l0 = blockIdx.x * 64;
    const int h = blockIdx.y, b = blockIdx.z;
    const size_t bh = ((size_t)b * 16 + h) * 1024;

    const float4* Q4 = (const float4*)Q;
    const float4* K4 = (const float4*)K;
    const float4* V4 = (const float4*)V;
    const float4* DE4 = (const float4*)de;
    const float4* MSK4 = (const float4*)mask;

    // this thread's 4 Q rows -> registers (only reader of these rows)
    float4 q[4][16];
#pragma unroll
    for (int ii = 0; ii < 4; ++ii)
#pragma unroll
        for (int u = 0; u < 16; ++u)
            q[ii][u] = Q4[(bh + l0 + ty * 4 + ii) * 16 + u];

    float m_r[4], l_r[4];
#pragma unroll
    for (int ii = 0; ii < 4; ++ii) { m_r[ii] = -1e30f; l_r[ii] = 0.f; }
    float o[4][4] = {};

    for (int r0 = 0; r0 < 1024; r0 += 64) {
        __syncthreads();   // prior-iter PV reads (P,V) done before restaging
        // stage K, V tiles
        for (int idx = tid; idx < 64 * 16; idx += 256) {
            int r = idx >> 4, u = idx & 15;
            KPs[swz(r, u)] = K4[(bh + r0 + r) * 16 + u];
            Vs[swz(r, u)]  = V4[(bh + r0 + r) * 16 + u];
        }
        // stage dist_emb window rows [tbase, tbase+126] as packed bf16
        const int tbase = l0 - r0 + 960;   // in [0, 1920]; +126 <= 2046 in-bounds
        for (int idx = tid; idx < 127 * 16; idx += 256) {
            int r = idx >> 4, u = idx & 15;
            float4 x = DE4[(size_t)(tbase + r) * 16 + u];
            uint2 p;
            p.x = pack_bf16(x.x, x.y);
            p.y = pack_bf16(x.z, x.w);
            Des[(r << 4) | (u ^ ((r >> 2) & 15))] = p;
        }
        __syncthreads();

        // ---- S tile: s = q.k + (q+k).de[l-r+1023]   (all in registers)
        float s[4][4] = {};
        const int dbase = 4 * (ty - tx) + 60;  // de row for (ii-jj) = -3; in [0,120]
#pragma unroll
        for (int d4 = 0; d4 < 16; ++d4) {
            float4 kv[4];
#pragma unroll
            for (int jj = 0; jj < 4; ++jj) kv[jj] = KPs[swz(tx * 4 + jj, d4)];
            float4 dv[7];
#pragma unroll
            for (int k = 0; k < 7; ++k) {
                int r = dbase + k;
                uint2 d2 = Des[(r << 4) | (d4 ^ ((r >> 2) & 15))];
                dv[k].x = __builtin_bit_cast(float, d2.x << 16);
                dv[k].y = __builtin_bit_cast(float, d2.x & 0xFFFF0000u);
                dv[k].z = __builtin_bit_cast(float, d2.y << 16);
                dv[k].w = __builtin_bit_cast(float, d2.y & 0xFFFF0000u);
            }
#pragma unroll
            for (int ii = 0; ii < 4; ++ii)
#pragma unroll
                for (int jj = 0; jj < 4; ++jj) {
                    const float4 qv = q[ii][d4], kk = kv[jj], dd = dv[ii - jj + 3];
                    s[ii][jj] += qv.x * kk.x + (qv.x + kk.x) * dd.x;
                    s[ii][jj] += qv.y * kk.y + (qv.y + kk.y) * dd.y;
                    s[ii][jj] += qv.z * kk.z + (qv.z + kk.z) * dd.z;
                    s[ii][jj] += qv.w * kk.w + (qv.w + kk.w) * dd.w;
                }
        }

        // ---- online softmax fully in registers (16 lanes per row group)
        float4 mv = MSK4[(b * 1024 + r0) / 4 + tx];
        float al[4];
#pragma unroll
        for (int ii = 0; ii < 4; ++ii) {
            float4 sv;
            sv.x = s[ii][0] * SCALE + mv.x;
            sv.y = s[ii][1] * SCALE + mv.y;
            sv.z = s[ii][2] * SCALE + mv.z;
            sv.w = s[ii][3] * SCALE + mv.w;
            float mx = fmaxf(fmaxf(sv.x, sv.y), fmaxf(sv.z, sv.w));
            mx = fmaxf(mx, __shfl_xor(mx, 1));
            mx = fmaxf(mx, __shfl_xor(mx, 2));
            mx = fmaxf(mx, __shfl_xor(mx, 4));
            mx = fmaxf(mx, __shfl_xor(mx, 8));
            float m_new = fmaxf(m_r[ii], mx);
            float a = __expf(m_r[ii] - m_new);
            sv.x = __expf(sv.x - m_new);
            sv.y = __expf(sv.y - m_new);
            sv.z = __expf(sv.z - m_new);
            sv.w = __expf(sv.w - m_new);
            float ssum = sv.x + sv.y + sv.z + sv.w;
            ssum += __shfl_xor(ssum, 1);
            ssum += __shfl_xor(ssum, 2);
            ssum += __shfl_xor(ssum, 4);
            ssum += __shfl_xor(ssum, 8);
            m_r[ii] = m_new;
            l_r[ii] = l_r[ii] * a + ssum;
            al[ii] = a;
            s[ii][0] = sv.x; s[ii][1] = sv.y; s[ii][2] = sv.z; s[ii][3] = sv.w;
        }
        __syncthreads();   // everyone done READING K before P overwrites it

        // write P into the K buffer
#pragma unroll
        for (int ii = 0; ii < 4; ++ii)
            KPs[swz(ty * 4 + ii, tx)] = make_float4(s[ii][0], s[ii][1], s[ii][2], s[ii][3]);
        __syncthreads();

        // ---- PV accumulate
#pragma unroll
        for (int ii = 0; ii < 4; ++ii)
#pragma unroll
            for (int jj = 0; jj < 4; ++jj) o[ii][jj] *= al[ii];
        for (int r4 = 0; r4 < 16; ++r4) {
            float4 p4[4], v4[4];
#pragma unroll
            for (int ii = 0; ii < 4; ++ii) p4[ii] = KPs[swz(ty * 4 + ii, r4)];
#pragma unroll
            for (int c = 0; c < 4; ++c) v4[c] = Vs[swz(r4 * 4 + c, tx)];
#pragma unroll
            for (int ii = 0; ii < 4; ++ii) {
                o[ii][0] += p4[ii].x * v4[0].x + p4[ii].y * v4[1].x + p4[ii].z * v4[2].x + p4[ii].w * v4[3].x;
                o[ii][1] += p4[ii].x * v4[0].y + p4[ii].y * v4[1].y + p4[ii].z * v4[2].y + p4[ii].w * v4[3].y;
                o[ii][2] += p4[ii].x * v4[0].z + p4[ii].y * v4[1].z + p4[ii].z * v4[2].z + p4[ii].w * v4[3].z;
                o[ii][3] += p4[ii].x * v4[0].w + p4[ii].y * v4[1].w + p4[ii].z * v4[2].w + p4[ii].w * v4[3].w;
            }
        }
    }

    // epilogue: out[b, l, h*64+d]
#pragma unroll
    for (int ii = 0; ii < 4; ++ii) {
        float inv = 1.0f / l_r[ii];
        float4 ov;
        ov.x = o[ii][0] * inv;
        ov.y = o[ii][1] * inv;
        ov.z = o[ii][2] * inv;
        ov.w = o[ii][3] * inv;
        *(float4*)&out[((size_t)(b * 1024 + l0 + ty * 4 + ii)) * 1024 + h * 64 + tx * 4] = ov;
    }
}

extern "C" void kernel_launch(void* const* d_in, const int* in_sizes, int n_in,
                              void* d_out, int out_size, void* d_ws, size_t ws_size,
                              hipStream_t stream) {
    const float* hs   = (const float*)d_in[0];
    const float* mask = (const float*)d_in[1];
    const float* Wq   = (const float*)d_in[2];
    const float* bq   = (const float*)d_in[3];
    const float* Wk   = (const float*)d_in[4];
    const float* bk   = (const float*)d_in[5];
    const float* Wv   = (const float*)d_in[6];
    const float* bv   = (const float*)d_in[7];
    const float* de   = (const float*)d_in[8];
    float* out = (float*)d_out;

    const size_t per = (size_t)4 * 16 * 1024 * 64;
    float* Qb = (float*)d_ws;
    float* Kb = Qb + per;
    float* Vb = Kb + per;

    dim3 pgrid(8, 32);
    proj_kernel<<<pgrid, 256, 0, stream>>>(hs, Wq, bq, Qb);
    proj_kernel<<<pgrid, 256, 0, stream>>>(hs, Wk, bk, Kb);
    proj_kernel<<<pgrid, 256, 0, stream>>>(hs, Wv, bv, Vb);

    dim3 agrid(16, 16, 4);
    attn_kernel<<<agrid, 256, 0, stream>>>(Qb, Kb, Vb, mask, de, out);
}

// Round 3
// 1118.853 us; speedup vs baseline: 3.4723x; 3.4723x over previous
//
#include <hip/hip_runtime.h>

// B=4, H=16, L=1024, D=1024, DH=64, P=1024
// q,k,v stored in ws as [B,H,L,DH] fp32

#define SCALE 0.125f  // 1/sqrt(64)

__device__ __forceinline__ int swz(int row, int u) {
    // 64-float rows = 16 float4 units; XOR-swizzle kills stride-64 conflicts
    return (row << 4) | (u ^ ((row >> 2) & 15));
}

__device__ __forceinline__ unsigned pack_bf16(float a, float b) {
    unsigned ua = __builtin_bit_cast(unsigned, a);
    unsigned ub = __builtin_bit_cast(unsigned, b);
    ua = (ua + 0x7FFFu + ((ua >> 16) & 1u)) >> 16;   // RNE
    ub = (ub + 0x7FFFu + ((ub >> 16) & 1u)) >> 16;
    return ua | (ub << 16);
}

// ---------------- projection GEMM (unchanged) ----------------
__global__ __launch_bounds__(256) void proj_kernel(
    const float* __restrict__ X, const float* __restrict__ W,
    const float* __restrict__ bias, float* __restrict__ out)
{
    __shared__ float4 As4[16 * 32];  // [k][m] transposed, 16x128 floats
    __shared__ float4 Bs4[16 * 32];  // [k][n], 16x128 floats
    const int tid = threadIdx.x;
    const int bm = blockIdx.y * 128;
    const int bn = blockIdx.x * 128;
    const int ty = tid >> 4, tx = tid & 15;
    const float4* X4 = (const float4*)X;
    const float4* W4 = (const float4*)W;
    float* AsF = (float*)As4;

    float acc[2][2][4][4];
#pragma unroll
    for (int a = 0; a < 2; ++a)
#pragma unroll
        for (int b = 0; b < 2; ++b)
#pragma unroll
            for (int i = 0; i < 4; ++i)
#pragma unroll
                for (int j = 0; j < 4; ++j) acc[a][b][i][j] = 0.f;

    for (int k0 = 0; k0 < 1024; k0 += 16) {
        __syncthreads();
#pragma unroll
        for (int it = 0; it < 2; ++it) {
            int idx = tid + it * 256;
            int m = idx >> 2, kc = idx & 3;
            float4 x = X4[(size_t)(bm + m) * 256 + (k0 >> 2) + kc];
            AsF[(kc * 4 + 0) * 128 + m] = x.x;
            AsF[(kc * 4 + 1) * 128 + m] = x.y;
            AsF[(kc * 4 + 2) * 128 + m] = x.z;
            AsF[(kc * 4 + 3) * 128 + m] = x.w;
        }
#pragma unroll
        for (int it = 0; it < 2; ++it) {
            int idx = tid + it * 256;
            int k = idx >> 5, un = idx & 31;
            Bs4[k * 32 + un] = W4[(size_t)(k0 + k) * 256 + (bn >> 2) + un];
        }
        __syncthreads();
#pragma unroll
        for (int kk = 0; kk < 16; ++kk) {
            float4 a0 = As4[kk * 32 + ty];
            float4 a1 = As4[kk * 32 + 16 + ty];
            float4 b0 = Bs4[kk * 32 + tx];
            float4 b1 = Bs4[kk * 32 + 16 + tx];
            float av[2][4] = {{a0.x, a0.y, a0.z, a0.w}, {a1.x, a1.y, a1.z, a1.w}};
            float bw[2][4] = {{b0.x, b0.y, b0.z, b0.w}, {b1.x, b1.y, b1.z, b1.w}};
#pragma unroll
            for (int rh = 0; rh < 2; ++rh)
#pragma unroll
                for (int ch = 0; ch < 2; ++ch)
#pragma unroll
                    for (int i = 0; i < 4; ++i)
#pragma unroll
                        for (int j = 0; j < 4; ++j)
                            acc[rh][ch][i][j] += av[rh][i] * bw[ch][j];
        }
    }
    const float4* bias4 = (const float4*)bias;
#pragma unroll
    for (int rh = 0; rh < 2; ++rh)
#pragma unroll
        for (int ch = 0; ch < 2; ++ch) {
            float4 bv4 = bias4[(bn >> 2) + ch * 16 + tx];
#pragma unroll
            for (int i = 0; i < 4; ++i) {
                int m = bm + rh * 64 + ty * 4 + i;
                int n = bn + ch * 64 + tx * 4;
                int b = m >> 10, l = m & 1023;
                int h = n >> 6, d = n & 63;
                float4 o;
                o.x = acc[rh][ch][i][0] + bv4.x;
                o.y = acc[rh][ch][i][1] + bv4.y;
                o.z = acc[rh][ch][i][2] + bv4.z;
                o.w = acc[rh][ch][i][3] + bv4.w;
                *(float4*)&out[(((size_t)b * 16 + h) * 1024 + l) * 64 + d] = o;
            }
        }
}

// ---------------- fused attention with relative_key_query bias ----------------
// one block = (b, h, 64 q-rows); Q in LDS (NOT regs — round-2 spill lesson);
// K/P union; De in bf16; softmax in registers via shfl
__global__ __launch_bounds__(256, 2) void attn_kernel(
    const float* __restrict__ Q, const float* __restrict__ K,
    const float* __restrict__ V, const float* __restrict__ mask,
    const float* __restrict__ de, float* __restrict__ out)
{
    __shared__ float4 Qs[64 * 16];    // 16 KB
    __shared__ float4 KPs[64 * 16];   // 16 KB: K during S-phase, P during PV
    __shared__ float4 Vs[64 * 16];    // 16 KB
    __shared__ uint2  Des[127 * 16];  // 15.9 KB: bf16x4 per 8B unit, swizzled

    const int tid = threadIdx.x;
    const int ty = tid >> 4, tx = tid & 15;   // 16x16 thread grid, 4x4 micro-tile
    const int l0 = blockIdx.x * 64;
    const int h = blockIdx.y, b = blockIdx.z;
    const size_t bh = ((size_t)b * 16 + h) * 1024;

    const float4* Q4 = (const float4*)Q;
    const float4* K4 = (const float4*)K;
    const float4* V4 = (const float4*)V;
    const float4* DE4 = (const float4*)de;
    const float4* MSK4 = (const float4*)mask;

    // stage Q once (visibility covered by first in-loop barrier)
    for (int idx = tid; idx < 64 * 16; idx += 256) {
        int r = idx >> 4, u = idx & 15;
        Qs[swz(r, u)] = Q4[(bh + l0 + r) * 16 + u];
    }

    float m_r[4], l_r[4];
#pragma unroll
    for (int ii = 0; ii < 4; ++ii) { m_r[ii] = -1e30f; l_r[ii] = 0.f; }
    float o[4][4] = {};

    for (int r0 = 0; r0 < 1024; r0 += 64) {
        __syncthreads();   // prior-iter PV reads (P,V) done before restaging
        // stage K, V tiles
        for (int idx = tid; idx < 64 * 16; idx += 256) {
            int r = idx >> 4, u = idx & 15;
            KPs[swz(r, u)] = K4[(bh + r0 + r) * 16 + u];
            Vs[swz(r, u)]  = V4[(bh + r0 + r) * 16 + u];
        }
        // stage dist_emb window rows [tbase, tbase+126] as packed bf16
        const int tbase = l0 - r0 + 960;   // in [0, 1920]; +126 <= 2046 in-bounds
        for (int idx = tid; idx < 127 * 16; idx += 256) {
            int r = idx >> 4, u = idx & 15;
            float4 x = DE4[(size_t)(tbase + r) * 16 + u];
            uint2 p;
            p.x = pack_bf16(x.x, x.y);
            p.y = pack_bf16(x.z, x.w);
            Des[(r << 4) | (u ^ ((r >> 2) & 15))] = p;
        }
        __syncthreads();

        // ---- S tile: s = q.k + (q+k).de[l-r+1023]
        float s[4][4] = {};
        const int dbase = 4 * (ty - tx) + 60;  // de row for (ii-jj) = -3; in [0,120]
        for (int d4 = 0; d4 < 16; ++d4) {
            float4 qv[4], kv[4];
#pragma unroll
            for (int ii = 0; ii < 4; ++ii) qv[ii] = Qs[swz(ty * 4 + ii, d4)];
#pragma unroll
            for (int jj = 0; jj < 4; ++jj) kv[jj] = KPs[swz(tx * 4 + jj, d4)];
            float4 dv[7];
#pragma unroll
            for (int k = 0; k < 7; ++k) {
                int r = dbase + k;
                uint2 d2 = Des[(r << 4) | (d4 ^ ((r >> 2) & 15))];
                dv[k].x = __builtin_bit_cast(float, d2.x << 16);
                dv[k].y = __builtin_bit_cast(float, d2.x & 0xFFFF0000u);
                dv[k].z = __builtin_bit_cast(float, d2.y << 16);
                dv[k].w = __builtin_bit_cast(float, d2.y & 0xFFFF0000u);
            }
#pragma unroll
            for (int ii = 0; ii < 4; ++ii)
#pragma unroll
                for (int jj = 0; jj < 4; ++jj) {
                    const float4 q = qv[ii], kk = kv[jj], dd = dv[ii - jj + 3];
                    s[ii][jj] += q.x * kk.x + (q.x + kk.x) * dd.x;
                    s[ii][jj] += q.y * kk.y + (q.y + kk.y) * dd.y;
                    s[ii][jj] += q.z * kk.z + (q.z + kk.z) * dd.z;
                    s[ii][jj] += q.w * kk.w + (q.w + kk.w) * dd.w;
                }
        }

        // ---- online softmax fully in registers (16 lanes per row group)
        float4 mv = MSK4[(b * 1024 + r0) / 4 + tx];
        float al[4];
#pragma unroll
        for (int ii = 0; ii < 4; ++ii) {
            float4 sv;
            sv.x = s[ii][0] * SCALE + mv.x;
            sv.y = s[ii][1] * SCALE + mv.y;
            sv.z = s[ii][2] * SCALE + mv.z;
            sv.w = s[ii][3] * SCALE + mv.w;
            float mx = fmaxf(fmaxf(sv.x, sv.y), fmaxf(sv.z, sv.w));
            mx = fmaxf(mx, __shfl_xor(mx, 1));
            mx = fmaxf(mx, __shfl_xor(mx, 2));
            mx = fmaxf(mx, __shfl_xor(mx, 4));
            mx = fmaxf(mx, __shfl_xor(mx, 8));
            float m_new = fmaxf(m_r[ii], mx);
            float a = __expf(m_r[ii] - m_new);
            sv.x = __expf(sv.x - m_new);
            sv.y = __expf(sv.y - m_new);
            sv.z = __expf(sv.z - m_new);
            sv.w = __expf(sv.w - m_new);
            float ssum = sv.x + sv.y + sv.z + sv.w;
            ssum += __shfl_xor(ssum, 1);
            ssum += __shfl_xor(ssum, 2);
            ssum += __shfl_xor(ssum, 4);
            ssum += __shfl_xor(ssum, 8);
            m_r[ii] = m_new;
            l_r[ii] = l_r[ii] * a + ssum;
            al[ii] = a;
            s[ii][0] = sv.x; s[ii][1] = sv.y; s[ii][2] = sv.z; s[ii][3] = sv.w;
        }
        __syncthreads();   // everyone done READING K before P overwrites it

        // write P into the K buffer
#pragma unroll
        for (int ii = 0; ii < 4; ++ii)
            KPs[swz(ty * 4 + ii, tx)] = make_float4(s[ii][0], s[ii][1], s[ii][2], s[ii][3]);
        __syncthreads();

        // ---- PV accumulate
#pragma unroll
        for (int ii = 0; ii < 4; ++ii)
#pragma unroll
            for (int jj = 0; jj < 4; ++jj) o[ii][jj] *= al[ii];
        for (int r4 = 0; r4 < 16; ++r4) {
            float4 p4[4], v4[4];
#pragma unroll
            for (int ii = 0; ii < 4; ++ii) p4[ii] = KPs[swz(ty * 4 + ii, r4)];
#pragma unroll
            for (int c = 0; c < 4; ++c) v4[c] = Vs[swz(r4 * 4 + c, tx)];
#pragma unroll
            for (int ii = 0; ii < 4; ++ii) {
                o[ii][0] += p4[ii].x * v4[0].x + p4[ii].y * v4[1].x + p4[ii].z * v4[2].x + p4[ii].w * v4[3].x;
                o[ii][1] += p4[ii].x * v4[0].y + p4[ii].y * v4[1].y + p4[ii].z * v4[2].y + p4[ii].w * v4[3].y;
                o[ii][2] += p4[ii].x * v4[0].z + p4[ii].y * v4[1].z + p4[ii].z * v4[2].z + p4[ii].w * v4[3].z;
                o[ii][3] += p4[ii].x * v4[0].w + p4[ii].y * v4[1].w + p4[ii].z * v4[2].w + p4[ii].w * v4[3].w;
            }
        }
    }

    // epilogue: out[b, l, h*64+d]
#pragma unroll
    for (int ii = 0; ii < 4; ++ii) {
        float inv = 1.0f / l_r[ii];
        float4 ov;
        ov.x = o[ii][0] * inv;
        ov.y = o[ii][1] * inv;
        ov.z = o[ii][2] * inv;
        ov.w = o[ii][3] * inv;
        *(float4*)&out[((size_t)(b * 1024 + l0 + ty * 4 + ii)) * 1024 + h * 64 + tx * 4] = ov;
    }
}

extern "C" void kernel_launch(void* const* d_in, const int* in_sizes, int n_in,
                              void* d_out, int out_size, void* d_ws, size_t ws_size,
                              hipStream_t stream) {
    const float* hs   = (const float*)d_in[0];
    const float* mask = (const float*)d_in[1];
    const float* Wq   = (const float*)d_in[2];
    const float* bq   = (const float*)d_in[3];
    const float* Wk   = (const float*)d_in[4];
    const float* bk   = (const float*)d_in[5];
    const float* Wv   = (const float*)d_in[6];
    const float* bv   = (const float*)d_in[7];
    const float* de   = (const float*)d_in[8];
    float* out = (float*)d_out;

    const size_t per = (size_t)4 * 16 * 1024 * 64;
    float* Qb = (float*)d_ws;
    float* Kb = Qb + per;
    float* Vb = Kb + per;

    dim3 pgrid(8, 32);
    proj_kernel<<<pgrid, 256, 0, stream>>>(hs, Wq, bq, Qb);
    proj_kernel<<<pgrid, 256, 0, stream>>>(hs, Wk, bk, Kb);
    proj_kernel<<<pgrid, 256, 0, stream>>>(hs, Wv, bv, Vb);

    dim3 agrid(16, 16, 4);
    attn_kernel<<<agrid, 256, 0, stream>>>(Qb, Kb, Vb, mask, de, out);
}

// Round 4
// 648.573 us; speedup vs baseline: 5.9900x; 1.7251x over previous
//
#include <hip/hip_runtime.h>

// B=4, H=16, L=1024, D=1024, DH=64, P=1024
// ws: Qhi,Qlo,Khi,Klo bf16 [B,H,L,64]; Vt bf16 [B,H,64,L]; de16 bf16 [2047,64]

#define SCALE 0.125f  // 1/sqrt(64)

typedef __attribute__((ext_vector_type(8))) short bf16x8;
typedef __attribute__((ext_vector_type(4))) float f32x4;
#define MFMA16(a, b, c) __builtin_amdgcn_mfma_f32_16x16x32_bf16(a, b, c, 0, 0, 0)

__device__ __forceinline__ unsigned short f2bf(float x) {
    unsigned u = __builtin_bit_cast(unsigned, x);
    return (unsigned short)((u + 0x7FFFu + ((u >> 16) & 1u)) >> 16);  // RNE
}
__device__ __forceinline__ float bf2f(unsigned short h) {
    unsigned u = ((unsigned)h) << 16;
    return __builtin_bit_cast(float, u);
}

// ---------------- projection GEMM: fp32 accumulate (unchanged math), bf16 epilogue ----
// MODE 0: out (Q/K) -> hi/lo bf16 [B,H,L,64].  MODE 1: out (V) -> bf16 transposed [B,H,64,L].
template <int MODE>
__global__ __launch_bounds__(256) void proj_kernel(
    const float* __restrict__ X, const float* __restrict__ W,
    const float* __restrict__ bias,
    unsigned short* __restrict__ outA, unsigned short* __restrict__ outB)
{
    __shared__ float4 As4[16 * 32];  // [k][m] transposed, 16x128 floats
    __shared__ float4 Bs4[16 * 32];  // [k][n], 16x128 floats
    const int tid = threadIdx.x;
    const int bm = blockIdx.y * 128;
    const int bn = blockIdx.x * 128;
    const int ty = tid >> 4, tx = tid & 15;
    const float4* X4 = (const float4*)X;
    const float4* W4 = (const float4*)W;
    float* AsF = (float*)As4;

    float acc[2][2][4][4];
#pragma unroll
    for (int a = 0; a < 2; ++a)
#pragma unroll
        for (int b = 0; b < 2; ++b)
#pragma unroll
            for (int i = 0; i < 4; ++i)
#pragma unroll
                for (int j = 0; j < 4; ++j) acc[a][b][i][j] = 0.f;

    for (int k0 = 0; k0 < 1024; k0 += 16) {
        __syncthreads();
#pragma unroll
        for (int it = 0; it < 2; ++it) {
            int idx = tid + it * 256;
            int m = idx >> 2, kc = idx & 3;
            float4 x = X4[(size_t)(bm + m) * 256 + (k0 >> 2) + kc];
            AsF[(kc * 4 + 0) * 128 + m] = x.x;
            AsF[(kc * 4 + 1) * 128 + m] = x.y;
            AsF[(kc * 4 + 2) * 128 + m] = x.z;
            AsF[(kc * 4 + 3) * 128 + m] = x.w;
        }
#pragma unroll
        for (int it = 0; it < 2; ++it) {
            int idx = tid + it * 256;
            int k = idx >> 5, un = idx & 31;
            Bs4[k * 32 + un] = W4[(size_t)(k0 + k) * 256 + (bn >> 2) + un];
        }
        __syncthreads();
#pragma unroll
        for (int kk = 0; kk < 16; ++kk) {
            float4 a0 = As4[kk * 32 + ty];
            float4 a1 = As4[kk * 32 + 16 + ty];
            float4 b0 = Bs4[kk * 32 + tx];
            float4 b1 = Bs4[kk * 32 + 16 + tx];
            float av[2][4] = {{a0.x, a0.y, a0.z, a0.w}, {a1.x, a1.y, a1.z, a1.w}};
            float bw[2][4] = {{b0.x, b0.y, b0.z, b0.w}, {b1.x, b1.y, b1.z, b1.w}};
#pragma unroll
            for (int rh = 0; rh < 2; ++rh)
#pragma unroll
                for (int ch = 0; ch < 2; ++ch)
#pragma unroll
                    for (int i = 0; i < 4; ++i)
#pragma unroll
                        for (int j = 0; j < 4; ++j)
                            acc[rh][ch][i][j] += av[rh][i] * bw[ch][j];
        }
    }
    const float4* bias4 = (const float4*)bias;
#pragma unroll
    for (int rh = 0; rh < 2; ++rh)
#pragma unroll
        for (int ch = 0; ch < 2; ++ch) {
            float4 bv4 = bias4[(bn >> 2) + ch * 16 + tx];
            float bj[4] = {bv4.x, bv4.y, bv4.z, bv4.w};
            if (MODE == 0) {
#pragma unroll
                for (int i = 0; i < 4; ++i) {
                    int m = bm + rh * 64 + ty * 4 + i;
                    int n = bn + ch * 64 + tx * 4;
                    int b = m >> 10, l = m & 1023;
                    int hh = n >> 6, d = n & 63;
                    size_t dst = (((size_t)b * 16 + hh) * 1024 + l) * 64 + d;
                    float v0 = acc[rh][ch][i][0] + bj[0];
                    float v1 = acc[rh][ch][i][1] + bj[1];
                    float v2 = acc[rh][ch][i][2] + bj[2];
                    float v3 = acc[rh][ch][i][3] + bj[3];
                    unsigned short h0 = f2bf(v0), h1 = f2bf(v1), h2 = f2bf(v2), h3 = f2bf(v3);
                    uint2 hi;
                    hi.x = (unsigned)h0 | ((unsigned)h1 << 16);
                    hi.y = (unsigned)h2 | ((unsigned)h3 << 16);
                    *(uint2*)&outA[dst] = hi;
                    unsigned short g0 = f2bf(v0 - bf2f(h0)), g1 = f2bf(v1 - bf2f(h1));
                    unsigned short g2 = f2bf(v2 - bf2f(h2)), g3 = f2bf(v3 - bf2f(h3));
                    uint2 lo;
                    lo.x = (unsigned)g0 | ((unsigned)g1 << 16);
                    lo.y = (unsigned)g2 | ((unsigned)g3 << 16);
                    *(uint2*)&outB[dst] = lo;
                }
            } else {
                // V: write transposed [B,H,64 d][1024 l], 4 consecutive l per store
                int m0 = bm + rh * 64 + ty * 4;
                int b = m0 >> 10, l = m0 & 1023;
#pragma unroll
                for (int j = 0; j < 4; ++j) {
                    int n = bn + ch * 64 + tx * 4 + j;
                    int hh = n >> 6, d = n & 63;
                    float v0 = acc[rh][ch][0][j] + bj[j];
                    float v1 = acc[rh][ch][1][j] + bj[j];
                    float v2 = acc[rh][ch][2][j] + bj[j];
                    float v3 = acc[rh][ch][3][j] + bj[j];
                    uint2 p;
                    p.x = (unsigned)f2bf(v0) | ((unsigned)f2bf(v1) << 16);
                    p.y = (unsigned)f2bf(v2) | ((unsigned)f2bf(v3) << 16);
                    *(uint2*)&outA[(((size_t)b * 16 + hh) * 64 + d) * 1024 + l] = p;
                }
            }
        }
}

// ---------------- dist_emb fp32 -> bf16 ----------------
__global__ __launch_bounds__(256) void conv_de(const float* __restrict__ de,
                                               unsigned short* __restrict__ de16)
{
    int gid = blockIdx.x * 256 + threadIdx.x;   // 8 elems each; 2047*64/8 = 16376
    if (gid >= 16376) return;
    const float4* s = (const float4*)(de + gid * 8);
    float4 a = s[0], c = s[1];
    uint4 p;
    p.x = (unsigned)f2bf(a.x) | ((unsigned)f2bf(a.y) << 16);
    p.y = (unsigned)f2bf(a.z) | ((unsigned)f2bf(a.w) << 16);
    p.z = (unsigned)f2bf(c.x) | ((unsigned)f2bf(c.y) << 16);
    p.w = (unsigned)f2bf(c.z) | ((unsigned)f2bf(c.w) << 16);
    *(uint4*)&de16[gid * 8] = p;
}

// ---------------- MFMA fused attention with relative_key_query bias ----------------
// block = (b,h,64 q-rows), 4 waves, each owns a 16-row strip.
// S = Qhi*Khi + Qlo*Khi + Qhi*Klo (split bf16); C=Q*PE^T, D=K*PE^T gathered per-diag.
__global__ __launch_bounds__(256, 2) void attn_kernel(
    const unsigned short* __restrict__ Qhi, const unsigned short* __restrict__ Qlo,
    const unsigned short* __restrict__ Khi, const unsigned short* __restrict__ Klo,
    const unsigned short* __restrict__ Vt,  const unsigned short* __restrict__ de16,
    const float* __restrict__ mask, float* __restrict__ out)
{
    __shared__ __align__(16) unsigned short KhiS[64 * 64];   //  8 KB
    __shared__ __align__(16) unsigned short KloS[64 * 64];   //  8 KB
    __shared__ __align__(16) unsigned short VtS [64 * 64];   //  8 KB  [d][r]
    __shared__ __align__(16) unsigned short PES [128 * 64];  // 16 KB  [t][d]
    __shared__ __align__(16) unsigned short CS  [64 * 128];  // 16 KB  [l][t]
    __shared__ __align__(16) unsigned short DS  [64 * 128];  // 16 KB  [r][t]
    __shared__ __align__(16) unsigned short PS  [64 * 64];   //  8 KB  [l][r]
    // total 80 KB -> 2 blocks/CU

    const int tid = threadIdx.x;
    const int wave = tid >> 6, lane = tid & 63;
    const int lr = lane & 15, lg = lane >> 4;
    const int l0 = blockIdx.x * 64;
    const int h = blockIdx.y, b = blockIdx.z;
    const size_t bh = (size_t)b * 16 + h;

    // Q A-fragments in registers: rows 16*wave + lr, k = kh*32 + lg*8 + i
    bf16x8 qh[2], ql[2];
    {
        size_t base = (bh * 1024 + l0 + wave * 16 + lr) * 64 + lg * 8;
        qh[0] = *(const bf16x8*)&Qhi[base];
        qh[1] = *(const bf16x8*)&Qhi[base + 32];
        ql[0] = *(const bf16x8*)&Qlo[base];
        ql[1] = *(const bf16x8*)&Qlo[base + 32];
    }

    const f32x4 fzero = {0.f, 0.f, 0.f, 0.f};
    f32x4 oacc[4];
#pragma unroll
    for (int dt = 0; dt < 4; ++dt) oacc[dt] = fzero;
    float m_r[4], l_r[4];
#pragma unroll
    for (int r = 0; r < 4; ++r) { m_r[r] = -1e30f; l_r[r] = 0.f; }

    for (int r0 = 0; r0 < 1024; r0 += 64) {
        __syncthreads();   // prev-iter PV done before restaging
        // ---- stage K hi/lo [r][d] and Vt [d][r], 16B units XOR-swizzled by row&7
#pragma unroll
        for (int it = 0; it < 2; ++it) {
            int idx = tid + it * 256;          // 0..511
            int r = idx >> 3, u = idx & 7;
            int us = u ^ (r & 7);
            *(uint4*)&KhiS[r * 64 + us * 8] = *(const uint4*)&Khi[(bh * 1024 + r0 + r) * 64 + u * 8];
            *(uint4*)&KloS[r * 64 + us * 8] = *(const uint4*)&Klo[(bh * 1024 + r0 + r) * 64 + u * 8];
            *(uint4*)&VtS [r * 64 + us * 8] = *(const uint4*)&Vt [(bh * 64 + r) * 1024 + r0 + u * 8];
        }
        // ---- stage PE window rows [tb, tb+127] (row 127 only feeds unused col)
        const int tb = l0 - r0 + 960;          // in [0,1920]
#pragma unroll
        for (int it = 0; it < 4; ++it) {
            int idx = tid + it * 256;          // 0..1023
            int r = idx >> 3, u = idx & 7;
            int rg = tb + r; if (rg > 2046) rg = 2046;
            int us = u ^ (r & 7);
            *(uint4*)&PES[r * 64 + us * 8] = *(const uint4*)&de16[(size_t)rg * 64 + u * 8];
        }
        __syncthreads();

        // ---- S = Q K^T (split bf16, fp32 acc)
        f32x4 sacc[4];
#pragma unroll
        for (int tt = 0; tt < 4; ++tt) {
            sacc[tt] = fzero;
            int rl = tt * 16 + lr;
#pragma unroll
            for (int kh = 0; kh < 2; ++kh) {
                int us = (kh * 4 + lg) ^ (rl & 7);
                bf16x8 kf = *(const bf16x8*)&KhiS[rl * 64 + us * 8];
                bf16x8 lf = *(const bf16x8*)&KloS[rl * 64 + us * 8];
                sacc[tt] = MFMA16(qh[kh], kf, sacc[tt]);
                sacc[tt] = MFMA16(ql[kh], kf, sacc[tt]);
                sacc[tt] = MFMA16(qh[kh], lf, sacc[tt]);
            }
        }

        // ---- C = Q*PE^T, D = K*PE^T for this wave's 16-row strip (fused PE reads)
        bf16x8 ka[2];
        {
            int rl = wave * 16 + lr;
#pragma unroll
            for (int kh = 0; kh < 2; ++kh) {
                int us = (kh * 4 + lg) ^ (rl & 7);
                ka[kh] = *(const bf16x8*)&KhiS[rl * 64 + us * 8];
            }
        }
        const int rowbase = wave * 16 + lg * 4;
#pragma unroll
        for (int tt = 0; tt < 8; ++tt) {
            int tl = tt * 16 + lr;
            f32x4 cacc = fzero, dacc = fzero;
#pragma unroll
            for (int kh = 0; kh < 2; ++kh) {
                int us = (kh * 4 + lg) ^ (tl & 7);
                bf16x8 pf = *(const bf16x8*)&PES[tl * 64 + us * 8];
                cacc = MFMA16(qh[kh], pf, cacc);
                dacc = MFMA16(ka[kh], pf, dacc);
            }
#pragma unroll
            for (int reg = 0; reg < 4; ++reg) {
                CS[(rowbase + reg) * 128 + tl] = f2bf(cacc[reg]);
                DS[(rowbase + reg) * 128 + tl] = f2bf(dacc[reg]);
            }
        }
        __syncthreads();   // C, D visible to all waves

        // ---- gather + online softmax on accumulators
        float mask_v[4];
#pragma unroll
        for (int tt = 0; tt < 4; ++tt) mask_v[tt] = mask[b * 1024 + r0 + tt * 16 + lr];
#pragma unroll
        for (int reg = 0; reg < 4; ++reg) {
            int ll = rowbase + reg;
            float sv[4];
#pragma unroll
            for (int tt = 0; tt < 4; ++tt) {
                int rl = tt * 16 + lr;
                int tw = ll - rl + 63;                       // [0,126]
                float cg = bf2f(CS[ll * 128 + tw]);
                float dg = bf2f(DS[rl * 128 + tw]);
                sv[tt] = (sacc[tt][reg] + cg + dg) * SCALE + mask_v[tt];
            }
            float mx = fmaxf(fmaxf(sv[0], sv[1]), fmaxf(sv[2], sv[3]));
            mx = fmaxf(mx, __shfl_xor(mx, 1));
            mx = fmaxf(mx, __shfl_xor(mx, 2));
            mx = fmaxf(mx, __shfl_xor(mx, 4));
            mx = fmaxf(mx, __shfl_xor(mx, 8));
            float mnew = fmaxf(m_r[reg], mx);
            float a = __expf(m_r[reg] - mnew);
            float sum = 0.f;
#pragma unroll
            for (int tt = 0; tt < 4; ++tt) { sv[tt] = __expf(sv[tt] - mnew); sum += sv[tt]; }
            sum += __shfl_xor(sum, 1);
            sum += __shfl_xor(sum, 2);
            sum += __shfl_xor(sum, 4);
            sum += __shfl_xor(sum, 8);
            m_r[reg] = mnew;
            l_r[reg] = l_r[reg] * a + sum;
#pragma unroll
            for (int dt = 0; dt < 4; ++dt) oacc[dt][reg] *= a;
#pragma unroll
            for (int tt = 0; tt < 4; ++tt) {
                int rl = tt * 16 + lr;
                PS[ll * 64 + (((rl >> 3) ^ (ll & 7)) << 3) + (rl & 7)] = f2bf(sv[tt]);
            }
        }
        __syncthreads();   // P ready

        // ---- PV: O += P V
        {
            int al = wave * 16 + lr;
#pragma unroll
            for (int kh = 0; kh < 2; ++kh) {
                int usa = (kh * 4 + lg) ^ (al & 7);
                bf16x8 pa = *(const bf16x8*)&PS[al * 64 + usa * 8];
#pragma unroll
                for (int dt = 0; dt < 4; ++dt) {
                    int dl = dt * 16 + lr;
                    int usb = (kh * 4 + lg) ^ (dl & 7);
                    bf16x8 vf = *(const bf16x8*)&VtS[dl * 64 + usb * 8];
                    oacc[dt] = MFMA16(pa, vf, oacc[dt]);
                }
            }
        }
    }

    // ---- epilogue: out[b, l, h*64+d] = O / l
    float inv[4];
#pragma unroll
    for (int reg = 0; reg < 4; ++reg) inv[reg] = 1.0f / l_r[reg];
#pragma unroll
    for (int dt = 0; dt < 4; ++dt)
#pragma unroll
        for (int reg = 0; reg < 4; ++reg) {
            int ll = wave * 16 + lg * 4 + reg;
            int dl = dt * 16 + lr;
            out[((size_t)b * 1024 + l0 + ll) * 1024 + h * 64 + dl] = oacc[dt][reg] * inv[reg];
        }
}

extern "C" void kernel_launch(void* const* d_in, const int* in_sizes, int n_in,
                              void* d_out, int out_size, void* d_ws, size_t ws_size,
                              hipStream_t stream) {
    const float* hs   = (const float*)d_in[0];
    const float* mask = (const float*)d_in[1];
    const float* Wq   = (const float*)d_in[2];
    const float* bq   = (const float*)d_in[3];
    const float* Wk   = (const float*)d_in[4];
    const float* bk   = (const float*)d_in[5];
    const float* Wv   = (const float*)d_in[6];
    const float* bv   = (const float*)d_in[7];
    const float* de   = (const float*)d_in[8];
    float* out = (float*)d_out;

    const size_t per = (size_t)4 * 16 * 1024 * 64;   // 4.19M elems
    unsigned short* Qhi = (unsigned short*)d_ws;
    unsigned short* Qlo = Qhi + per;
    unsigned short* Khi = Qlo + per;
    unsigned short* Klo = Khi + per;
    unsigned short* Vtb = Klo + per;
    unsigned short* de16 = Vtb + per;   // 2047*64 elems; total ~42.2 MB

    dim3 pgrid(8, 32);
    proj_kernel<0><<<pgrid, 256, 0, stream>>>(hs, Wq, bq, Qhi, Qlo);
    proj_kernel<0><<<pgrid, 256, 0, stream>>>(hs, Wk, bk, Khi, Klo);
    proj_kernel<1><<<pgrid, 256, 0, stream>>>(hs, Wv, bv, Vtb, Vtb);
    conv_de<<<64, 256, 0, stream>>>(de, de16);

    dim3 agrid(16, 16, 4);
    attn_kernel<<<agrid, 256, 0, stream>>>(Qhi, Qlo, Khi, Klo, Vtb, de16, mask, out);
}

// Round 5
// 318.730 us; speedup vs baseline: 12.1888x; 2.0349x over previous
//
#include <hip/hip_runtime.h>

// B=4, H=16, L=1024, D=1024, DH=64, P=1024
// ws: Qhi,Qlo,Khi,Klo bf16 [B,H,L,64]; Vt bf16 [B,H,64,L]; Xhi,Xlo bf16 [4096,1024];
//     Wthi,Wtlo bf16 [3072,1024] (n-major, Wq|Wk|Wv); de16 bf16 [2047,64]

#define SCALE 0.125f  // 1/sqrt(64)

typedef __attribute__((ext_vector_type(8))) short bf16x8;
typedef __attribute__((ext_vector_type(4))) float f32x4;
#define MFMA16(a, b, c) __builtin_amdgcn_mfma_f32_16x16x32_bf16(a, b, c, 0, 0, 0)

__device__ __forceinline__ unsigned short f2bf(float x) {
    unsigned u = __builtin_bit_cast(unsigned, x);
    return (unsigned short)((u + 0x7FFFu + ((u >> 16) & 1u)) >> 16);  // RNE
}
__device__ __forceinline__ float bf2f(unsigned short h) {
    unsigned u = ((unsigned)h) << 16;
    return __builtin_bit_cast(float, u);
}

// ---------------- X fp32 -> hi/lo bf16 (same [m][k] layout) ----------------
__global__ __launch_bounds__(256) void conv_x(const float* __restrict__ x,
                                              unsigned short* __restrict__ xhi,
                                              unsigned short* __restrict__ xlo)
{
    size_t gid = (size_t)blockIdx.x * 256 + threadIdx.x;   // 8 elems each; 4096*1024/8
    const float4* s = (const float4*)(x + gid * 8);
    float4 a = s[0], b = s[1];
    float v[8] = {a.x, a.y, a.z, a.w, b.x, b.y, b.z, b.w};
    unsigned hi[4], lo[4];
#pragma unroll
    for (int i = 0; i < 4; ++i) {
        unsigned short h0 = f2bf(v[2 * i]), h1 = f2bf(v[2 * i + 1]);
        hi[i] = (unsigned)h0 | ((unsigned)h1 << 16);
        unsigned short g0 = f2bf(v[2 * i] - bf2f(h0)), g1 = f2bf(v[2 * i + 1] - bf2f(h1));
        lo[i] = (unsigned)g0 | ((unsigned)g1 << 16);
    }
    *(uint4*)&xhi[gid * 8] = make_uint4(hi[0], hi[1], hi[2], hi[3]);
    *(uint4*)&xlo[gid * 8] = make_uint4(lo[0], lo[1], lo[2], lo[3]);
}

// ---------------- W [k][n] fp32 -> Wt [n + which*1024][k] hi/lo bf16 ----------------
__global__ __launch_bounds__(256) void conv_w(const float* __restrict__ Wq,
                                              const float* __restrict__ Wk,
                                              const float* __restrict__ Wv,
                                              unsigned short* __restrict__ wthi,
                                              unsigned short* __restrict__ wtlo)
{
    __shared__ float T[64][68];   // [k][n] tile, padded
    const int which = blockIdx.z;
    const float* W = which == 0 ? Wq : which == 1 ? Wk : Wv;
    const int k0 = blockIdx.y * 64, n0 = blockIdx.x * 64;
    const int ty = threadIdx.x >> 4, tx = threadIdx.x & 15;
#pragma unroll
    for (int i = 0; i < 4; ++i) {
        float4 v = *(const float4*)&W[(size_t)(k0 + ty * 4 + i) * 1024 + n0 + tx * 4];
        T[ty * 4 + i][tx * 4 + 0] = v.x;
        T[ty * 4 + i][tx * 4 + 1] = v.y;
        T[ty * 4 + i][tx * 4 + 2] = v.z;
        T[ty * 4 + i][tx * 4 + 3] = v.w;
    }
    __syncthreads();
#pragma unroll
    for (int i = 0; i < 4; ++i) {
        int n = n0 + ty * 4 + i;
        unsigned hi[2], lo[2];
#pragma unroll
        for (int p = 0; p < 2; ++p) {
            float v0 = T[tx * 4 + 2 * p][ty * 4 + i];
            float v1 = T[tx * 4 + 2 * p + 1][ty * 4 + i];
            unsigned short h0 = f2bf(v0), h1 = f2bf(v1);
            hi[p] = (unsigned)h0 | ((unsigned)h1 << 16);
            unsigned short g0 = f2bf(v0 - bf2f(h0)), g1 = f2bf(v1 - bf2f(h1));
            lo[p] = (unsigned)g0 | ((unsigned)g1 << 16);
        }
        size_t dst = (size_t)(which * 1024 + n) * 1024 + k0 + tx * 4;
        *(uint2*)&wthi[dst] = make_uint2(hi[0], hi[1]);
        *(uint2*)&wtlo[dst] = make_uint2(lo[0], lo[1]);
    }
}

// ---------------- dist_emb fp32 -> bf16 ----------------
__global__ __launch_bounds__(256) void conv_de(const float* __restrict__ de,
                                               unsigned short* __restrict__ de16)
{
    int gid = blockIdx.x * 256 + threadIdx.x;   // 8 elems each; 2047*64/8 = 16376
    if (gid >= 16376) return;
    const float4* s = (const float4*)(de + gid * 8);
    float4 a = s[0], c = s[1];
    uint4 p;
    p.x = (unsigned)f2bf(a.x) | ((unsigned)f2bf(a.y) << 16);
    p.y = (unsigned)f2bf(a.z) | ((unsigned)f2bf(a.w) << 16);
    p.z = (unsigned)f2bf(c.x) | ((unsigned)f2bf(c.y) << 16);
    p.w = (unsigned)f2bf(c.z) | ((unsigned)f2bf(c.w) << 16);
    *(uint4*)&de16[gid * 8] = p;
}

// ---------------- fused QKV projection: split-bf16 MFMA GEMM ----------------
// M=4096 (b,l), N=3072 (which,h,d), K=1024. 128x128 tile, 4 waves of 64x64.
// S = Ah*Bh + Al*Bh + Ah*Bl (fp32-grade). Epilogue: Q/K hi+lo bf16, V transposed bf16.
__global__ __launch_bounds__(256, 2) void qkv_gemm(
    const unsigned short* __restrict__ Xhi, const unsigned short* __restrict__ Xlo,
    const unsigned short* __restrict__ Wthi, const unsigned short* __restrict__ Wtlo,
    const float* __restrict__ bq, const float* __restrict__ bk, const float* __restrict__ bv,
    unsigned short* __restrict__ Qhi, unsigned short* __restrict__ Qlo,
    unsigned short* __restrict__ Khi, unsigned short* __restrict__ Klo,
    unsigned short* __restrict__ Vt)
{
    __shared__ __align__(16) unsigned short AhiS[128 * 64];  // 16 KB each
    __shared__ __align__(16) unsigned short AloS[128 * 64];
    __shared__ __align__(16) unsigned short BhiS[128 * 64];
    __shared__ __align__(16) unsigned short BloS[128 * 64];

    const int tid = threadIdx.x;
    const int wave = tid >> 6, lane = tid & 63;
    const int lr = lane & 15, lg = lane >> 4;
    const int wr = wave >> 1, wc = wave & 1;
    const int m0 = blockIdx.y * 128, n0 = blockIdx.x * 128;

    const f32x4 fzero = {0.f, 0.f, 0.f, 0.f};
    f32x4 acc[4][4];
#pragma unroll
    for (int i = 0; i < 4; ++i)
#pragma unroll
        for (int j = 0; j < 4; ++j) acc[i][j] = fzero;

    for (int k0 = 0; k0 < 1024; k0 += 64) {
        __syncthreads();
#pragma unroll
        for (int t = 0; t < 4; ++t) {
            int idx = tid + t * 256;        // 0..1023 16B-units
            int r = idx >> 3, u = idx & 7;
            int us = u ^ (r & 7);
            *(uint4*)&AhiS[r * 64 + us * 8] = *(const uint4*)&Xhi[(size_t)(m0 + r) * 1024 + k0 + u * 8];
            *(uint4*)&AloS[r * 64 + us * 8] = *(const uint4*)&Xlo[(size_t)(m0 + r) * 1024 + k0 + u * 8];
            *(uint4*)&BhiS[r * 64 + us * 8] = *(const uint4*)&Wthi[(size_t)(n0 + r) * 1024 + k0 + u * 8];
            *(uint4*)&BloS[r * 64 + us * 8] = *(const uint4*)&Wtlo[(size_t)(n0 + r) * 1024 + k0 + u * 8];
        }
        __syncthreads();
#pragma unroll
        for (int kh = 0; kh < 2; ++kh) {
            bf16x8 ah[4], al[4], bh[4], bl[4];
#pragma unroll
            for (int i = 0; i < 4; ++i) {
                int mrow = wr * 64 + i * 16 + lr;
                int usa = (kh * 4 + lg) ^ (mrow & 7);
                ah[i] = *(const bf16x8*)&AhiS[mrow * 64 + usa * 8];
                al[i] = *(const bf16x8*)&AloS[mrow * 64 + usa * 8];
                int nrow = wc * 64 + i * 16 + lr;
                int usb = (kh * 4 + lg) ^ (nrow & 7);
                bh[i] = *(const bf16x8*)&BhiS[nrow * 64 + usb * 8];
                bl[i] = *(const bf16x8*)&BloS[nrow * 64 + usb * 8];
            }
#pragma unroll
            for (int am = 0; am < 4; ++am)
#pragma unroll
                for (int bn = 0; bn < 4; ++bn) {
                    acc[am][bn] = MFMA16(ah[am], bh[bn], acc[am][bn]);
                    acc[am][bn] = MFMA16(al[am], bh[bn], acc[am][bn]);
                    acc[am][bn] = MFMA16(ah[am], bl[bn], acc[am][bn]);
                }
        }
    }

    // ---- epilogue
    const int which = n0 >> 10;    // tile never straddles a 1024 boundary
    const float* bsel = which == 0 ? bq : which == 1 ? bk : bv;
#pragma unroll
    for (int bn = 0; bn < 4; ++bn) {
        int n_g = n0 + wc * 64 + bn * 16 + lr;
        float bias = bsel[n_g & 1023];
        int hh = (n_g >> 6) & 15, d = n_g & 63;
#pragma unroll
        for (int am = 0; am < 4; ++am) {
#pragma unroll
            for (int reg = 0; reg < 4; ++reg) {
                int m_g = m0 + wr * 64 + am * 16 + lg * 4 + reg;
                int bb = m_g >> 10, l = m_g & 1023;
                float v = acc[am][bn][reg] + bias;
                if (which == 2) {
                    Vt[(((size_t)bb * 16 + hh) * 64 + d) * 1024 + l] = f2bf(v);
                } else {
                    size_t dst = (((size_t)bb * 16 + hh) * 1024 + l) * 64 + d;
                    unsigned short hi = f2bf(v);
                    unsigned short lo = f2bf(v - bf2f(hi));
                    if (which == 0) { Qhi[dst] = hi; Qlo[dst] = lo; }
                    else            { Khi[dst] = hi; Klo[dst] = lo; }
                }
            }
        }
    }
}

// ---------------- MFMA fused attention with relative_key_query bias (unchanged) ----------
__global__ __launch_bounds__(256, 2) void attn_kernel(
    const unsigned short* __restrict__ Qhi, const unsigned short* __restrict__ Qlo,
    const unsigned short* __restrict__ Khi, const unsigned short* __restrict__ Klo,
    const unsigned short* __restrict__ Vt,  const unsigned short* __restrict__ de16,
    const float* __restrict__ mask, float* __restrict__ out)
{
    __shared__ __align__(16) unsigned short KhiS[64 * 64];   //  8 KB
    __shared__ __align__(16) unsigned short KloS[64 * 64];   //  8 KB
    __shared__ __align__(16) unsigned short VtS [64 * 64];   //  8 KB  [d][r]
    __shared__ __align__(16) unsigned short PES [128 * 64];  // 16 KB  [t][d]
    __shared__ __align__(16) unsigned short CS  [64 * 128];  // 16 KB  [l][t]
    __shared__ __align__(16) unsigned short DS  [64 * 128];  // 16 KB  [r][t]
    __shared__ __align__(16) unsigned short PS  [64 * 64];   //  8 KB  [l][r]

    const int tid = threadIdx.x;
    const int wave = tid >> 6, lane = tid & 63;
    const int lr = lane & 15, lg = lane >> 4;
    const int l0 = blockIdx.x * 64;
    const int h = blockIdx.y, b = blockIdx.z;
    const size_t bh = (size_t)b * 16 + h;

    bf16x8 qh[2], ql[2];
    {
        size_t base = (bh * 1024 + l0 + wave * 16 + lr) * 64 + lg * 8;
        qh[0] = *(const bf16x8*)&Qhi[base];
        qh[1] = *(const bf16x8*)&Qhi[base + 32];
        ql[0] = *(const bf16x8*)&Qlo[base];
        ql[1] = *(const bf16x8*)&Qlo[base + 32];
    }

    const f32x4 fzero = {0.f, 0.f, 0.f, 0.f};
    f32x4 oacc[4];
#pragma unroll
    for (int dt = 0; dt < 4; ++dt) oacc[dt] = fzero;
    float m_r[4], l_r[4];
#pragma unroll
    for (int r = 0; r < 4; ++r) { m_r[r] = -1e30f; l_r[r] = 0.f; }

    for (int r0 = 0; r0 < 1024; r0 += 64) {
        __syncthreads();
#pragma unroll
        for (int it = 0; it < 2; ++it) {
            int idx = tid + it * 256;
            int r = idx >> 3, u = idx & 7;
            int us = u ^ (r & 7);
            *(uint4*)&KhiS[r * 64 + us * 8] = *(const uint4*)&Khi[(bh * 1024 + r0 + r) * 64 + u * 8];
            *(uint4*)&KloS[r * 64 + us * 8] = *(const uint4*)&Klo[(bh * 1024 + r0 + r) * 64 + u * 8];
            *(uint4*)&VtS [r * 64 + us * 8] = *(const uint4*)&Vt [(bh * 64 + r) * 1024 + r0 + u * 8];
        }
        const int tb = l0 - r0 + 960;
#pragma unroll
        for (int it = 0; it < 4; ++it) {
            int idx = tid + it * 256;
            int r = idx >> 3, u = idx & 7;
            int rg = tb + r; if (rg > 2046) rg = 2046;
            int us = u ^ (r & 7);
            *(uint4*)&PES[r * 64 + us * 8] = *(const uint4*)&de16[(size_t)rg * 64 + u * 8];
        }
        __syncthreads();

        f32x4 sacc[4];
#pragma unroll
        for (int tt = 0; tt < 4; ++tt) {
            sacc[tt] = fzero;
            int rl = tt * 16 + lr;
#pragma unroll
            for (int kh = 0; kh < 2; ++kh) {
                int us = (kh * 4 + lg) ^ (rl & 7);
                bf16x8 kf = *(const bf16x8*)&KhiS[rl * 64 + us * 8];
                bf16x8 lf = *(const bf16x8*)&KloS[rl * 64 + us * 8];
                sacc[tt] = MFMA16(qh[kh], kf, sacc[tt]);
                sacc[tt] = MFMA16(ql[kh], kf, sacc[tt]);
                sacc[tt] = MFMA16(qh[kh], lf, sacc[tt]);
            }
        }

        bf16x8 ka[2];
        {
            int rl = wave * 16 + lr;
#pragma unroll
            for (int kh = 0; kh < 2; ++kh) {
                int us = (kh * 4 + lg) ^ (rl & 7);
                ka[kh] = *(const bf16x8*)&KhiS[rl * 64 + us * 8];
            }
        }
        const int rowbase = wave * 16 + lg * 4;
#pragma unroll
        for (int tt = 0; tt < 8; ++tt) {
            int tl = tt * 16 + lr;
            f32x4 cacc = fzero, dacc = fzero;
#pragma unroll
            for (int kh = 0; kh < 2; ++kh) {
                int us = (kh * 4 + lg) ^ (tl & 7);
                bf16x8 pf = *(const bf16x8*)&PES[tl * 64 + us * 8];
                cacc = MFMA16(qh[kh], pf, cacc);
                dacc = MFMA16(ka[kh], pf, dacc);
            }
#pragma unroll
            for (int reg = 0; reg < 4; ++reg) {
                CS[(rowbase + reg) * 128 + tl] = f2bf(cacc[reg]);
                DS[(rowbase + reg) * 128 + tl] = f2bf(dacc[reg]);
            }
        }
        __syncthreads();

        float mask_v[4];
#pragma unroll
        for (int tt = 0; tt < 4; ++tt) mask_v[tt] = mask[b * 1024 + r0 + tt * 16 + lr];
#pragma unroll
        for (int reg = 0; reg < 4; ++reg) {
            int ll = rowbase + reg;
            float sv[4];
#pragma unroll
            for (int tt = 0; tt < 4; ++tt) {
                int rl = tt * 16 + lr;
                int tw = ll - rl + 63;
                float cg = bf2f(CS[ll * 128 + tw]);
                float dg = bf2f(DS[rl * 128 + tw]);
                sv[tt] = (sacc[tt][reg] + cg + dg) * SCALE + mask_v[tt];
            }
            float mx = fmaxf(fmaxf(sv[0], sv[1]), fmaxf(sv[2], sv[3]));
            mx = fmaxf(mx, __shfl_xor(mx, 1));
            mx = fmaxf(mx, __shfl_xor(mx, 2));
            mx = fmaxf(mx, __shfl_xor(mx, 4));
            mx = fmaxf(mx, __shfl_xor(mx, 8));
            float mnew = fmaxf(m_r[reg], mx);
            float a = __expf(m_r[reg] - mnew);
            float sum = 0.f;
#pragma unroll
            for (int tt = 0; tt < 4; ++tt) { sv[tt] = __expf(sv[tt] - mnew); sum += sv[tt]; }
            sum += __shfl_xor(sum, 1);
            sum += __shfl_xor(sum, 2);
            sum += __shfl_xor(sum, 4);
            sum += __shfl_xor(sum, 8);
            m_r[reg] = mnew;
            l_r[reg] = l_r[reg] * a + sum;
#pragma unroll
            for (int dt = 0; dt < 4; ++dt) oacc[dt][reg] *= a;
#pragma unroll
            for (int tt = 0; tt < 4; ++tt) {
                int rl = tt * 16 + lr;
                PS[ll * 64 + (((rl >> 3) ^ (ll & 7)) << 3) + (rl & 7)] = f2bf(sv[tt]);
            }
        }
        __syncthreads();

        {
            int alr = wave * 16 + lr;
#pragma unroll
            for (int kh = 0; kh < 2; ++kh) {
                int usa = (kh * 4 + lg) ^ (alr & 7);
                bf16x8 pa = *(const bf16x8*)&PS[alr * 64 + usa * 8];
#pragma unroll
                for (int dt = 0; dt < 4; ++dt) {
                    int dl = dt * 16 + lr;
                    int usb = (kh * 4 + lg) ^ (dl & 7);
                    bf16x8 vf = *(const bf16x8*)&VtS[dl * 64 + usb * 8];
                    oacc[dt] = MFMA16(pa, vf, oacc[dt]);
                }
            }
        }
    }

    float inv[4];
#pragma unroll
    for (int reg = 0; reg < 4; ++reg) inv[reg] = 1.0f / l_r[reg];
#pragma unroll
    for (int dt = 0; dt < 4; ++dt)
#pragma unroll
        for (int reg = 0; reg < 4; ++reg) {
            int ll = wave * 16 + lg * 4 + reg;
            int dl = dt * 16 + lr;
            out[((size_t)b * 1024 + l0 + ll) * 1024 + h * 64 + dl] = oacc[dt][reg] * inv[reg];
        }
}

extern "C" void kernel_launch(void* const* d_in, const int* in_sizes, int n_in,
                              void* d_out, int out_size, void* d_ws, size_t ws_size,
                              hipStream_t stream) {
    const float* hs   = (const float*)d_in[0];
    const float* mask = (const float*)d_in[1];
    const float* Wq   = (const float*)d_in[2];
    const float* bq   = (const float*)d_in[3];
    const float* Wk   = (const float*)d_in[4];
    const float* bk   = (const float*)d_in[5];
    const float* Wv   = (const float*)d_in[6];
    const float* bv   = (const float*)d_in[7];
    const float* de   = (const float*)d_in[8];
    float* out = (float*)d_out;

    const size_t per = (size_t)4 * 16 * 1024 * 64;   // 4.19M elems (also = 4096*1024)
    unsigned short* Qhi  = (unsigned short*)d_ws;
    unsigned short* Qlo  = Qhi + per;
    unsigned short* Khi  = Qlo + per;
    unsigned short* Klo  = Khi + per;
    unsigned short* Vtb  = Klo + per;
    unsigned short* Xhi  = Vtb + per;
    unsigned short* Xlo  = Xhi + per;
    unsigned short* Wthi = Xlo + per;
    unsigned short* Wtlo = Wthi + (size_t)3072 * 1024;
    unsigned short* de16 = Wtlo + (size_t)3072 * 1024;   // ~72 MB total

    conv_x<<<2048, 256, 0, stream>>>(hs, Xhi, Xlo);
    conv_w<<<dim3(16, 16, 3), 256, 0, stream>>>(Wq, Wk, Wv, Wthi, Wtlo);
    conv_de<<<64, 256, 0, stream>>>(de, de16);

    qkv_gemm<<<dim3(24, 32), 256, 0, stream>>>(Xhi, Xlo, Wthi, Wtlo, bq, bk, bv,
                                               Qhi, Qlo, Khi, Klo, Vtb);

    dim3 agrid(16, 16, 4);
    attn_kernel<<<agrid, 256, 0, stream>>>(Qhi, Qlo, Khi, Klo, Vtb, de16, mask, out);
}